// Round 7
// baseline (1043.107 us; speedup 1.0000x reference)
//
#include <hip/hip_runtime.h>
#include <math.h>

namespace {
constexpr int kB = 32;
constexpr int kNP = 350;
constexpr int kNL = 30;
constexpr int kNG = 380;
constexpr int kN = kB * kNG;      // 12160
constexpr int kG = 20;
constexpr int kNPROT = kB * kNP;  // 11200
constexpr int kNLIG = kB * kNL;   // 960
constexpr int TP = 32;            // protein tile
constexpr int NT = 11;            // tiles (10*32 + 30)
}  // namespace

// ---------------------------------------------------------------------------
// Kernel A: node-level precompute (unchanged from R2 — passed).
// ---------------------------------------------------------------------------
__global__ __launch_bounds__(256) void pre_kernel(
    const float* __restrict__ h,
    const float* __restrict__ wk1, const float* __restrict__ bk1,
    const float* __restrict__ wv1, const float* __restrict__ bv1,
    const float* __restrict__ wx1, const float* __restrict__ bx1,
    float* __restrict__ outKd, float* __restrict__ outVd, float* __restrict__ outXd,
    float* __restrict__ outKs, float* __restrict__ outVs, float* __restrict__ outXs) {
  const int m = blockIdx.y;
  const float* w1 = (m == 0) ? wk1 : (m == 1) ? wv1 : wx1;
  const float* b1 = (m == 0) ? bk1 : (m == 1) ? bv1 : bx1;
  const bool isProt = (blockIdx.x < 175);
  const int rbase = isProt ? blockIdx.x * 64 : (blockIdx.x - 175) * 64;
  float* outArr = isProt ? ((m == 0) ? outKd : (m == 1) ? outVd : outXd)
                         : ((m == 0) ? outKs : (m == 1) ? outVs : outXs);
  const float* wb = w1 + (isProt ? 20 * 128 : 148 * 128);

  __shared__ float sh[64 * 132];
  const int t = threadIdx.x;
#pragma unroll
  for (int j = 0; j < 8; ++j) {
    int flat = t + j * 256;
    int row = flat >> 5;
    int col = (flat & 31) * 4;
    int r = rbase + row;
    int node;
    if (isProt) node = (r / kNP) * kNG + (r % kNP);
    else        node = (r / kNL) * kNG + kNP + (r % kNL);
    *(float4*)&sh[row * 132 + col] = *(const float4*)(h + (size_t)node * 128 + col);
  }
  __syncthreads();

  const int dcol = (t & 31) * 4;
  const int rrow = (t >> 5) * 8;
  float4 acc[8];
#pragma unroll
  for (int i = 0; i < 8; ++i) acc[i] = make_float4(0.f, 0.f, 0.f, 0.f);

  for (int k = 0; k < 128; k += 4) {
    float4 a4[8];
#pragma unroll
    for (int i = 0; i < 8; ++i) a4[i] = *(float4*)&sh[(rrow + i) * 132 + k];
#pragma unroll
    for (int kk = 0; kk < 4; ++kk) {
      float4 w4 = *(const float4*)(wb + (size_t)(k + kk) * 128 + dcol);
#pragma unroll
      for (int i = 0; i < 8; ++i) {
        float a = (kk == 0) ? a4[i].x : (kk == 1) ? a4[i].y : (kk == 2) ? a4[i].z : a4[i].w;
        acc[i].x += a * w4.x; acc[i].y += a * w4.y;
        acc[i].z += a * w4.z; acc[i].w += a * w4.w;
      }
    }
  }
  float4 bias = make_float4(0.f, 0.f, 0.f, 0.f);
  if (!isProt) bias = *(const float4*)(b1 + dcol);
#pragma unroll
  for (int i = 0; i < 8; ++i) {
    float4 o = acc[i];
    o.x += bias.x; o.y += bias.y; o.z += bias.z; o.w += bias.w;
    *(float4*)(outArr + (size_t)(rbase + rrow + i) * 128 + dcol) = o;
  }
}

// ---------------------------------------------------------------------------
// Kernel cvec (unchanged).
// ---------------------------------------------------------------------------
__global__ __launch_bounds__(128) void cvec_kernel(
    const float* __restrict__ h,
    const float* __restrict__ no_w1, const float* __restrict__ no_b1,
    const float* __restrict__ no_g, const float* __restrict__ no_be,
    const float* __restrict__ no_w2, const float* __restrict__ no_b2,
    float* __restrict__ cvec) {
  __shared__ float sy[128];
  __shared__ float sa[128];
  __shared__ float red[2];
  const int d = threadIdx.x;
  float y = no_b1[d];
  for (int i = 0; i < 128; ++i) y += h[i] * no_w1[(size_t)(128 + i) * 128 + d];
  sy[d] = y;
  __syncthreads();
  if (d == 0) {
    float s = 0.f, ss = 0.f;
    for (int i = 0; i < 128; ++i) { s += sy[i]; ss += sy[i] * sy[i]; }
    float mu = s / 128.f;
    red[0] = mu;
    red[1] = rsqrtf(ss / 128.f - mu * mu + 1e-5f);
  }
  __syncthreads();
  float a = (y - red[0]) * red[1] * no_g[d] + no_be[d];
  sa[d] = fmaxf(a, 0.f);
  __syncthreads();
  float o = no_b2[d];
  for (int i = 0; i < 128; ++i) o += sa[i] * no_w2[(size_t)i * 128 + d];
  cvec[d] = o;
}

// ---------------------------------------------------------------------------
// Kernel D: protein nodes (unchanged).
// ---------------------------------------------------------------------------
__global__ __launch_bounds__(256) void prot_kernel(
    const float* __restrict__ h, const float* __restrict__ x,
    const float* __restrict__ cvec, float* __restrict__ hout, float* __restrict__ xout) {
  int idx = blockIdx.x * 256 + threadIdx.x;
  if (idx < kNPROT * 32) {
    int r = idx >> 5, c4 = (idx & 31) * 4;
    int node = (r / kNP) * kNG + (r % kNP);
    float4 hv = *(const float4*)(h + (size_t)node * 128 + c4);
    float4 cv = *(const float4*)(cvec + c4);
    *(float4*)(hout + (size_t)node * 128 + c4) =
        make_float4(hv.x + cv.x, hv.y + cv.y, hv.z + cv.z, hv.w + cv.w);
  }
  if (idx < kNPROT * 3) {
    int r = idx / 3, c = idx % 3;
    int node = (r / kNP) * kNG + (r % kNP);
    xout[(size_t)node * 3 + c] = x[(size_t)node * 3 + c];
  }
}

// ---------------------------------------------------------------------------
// Kernel B: one WG per ligand. 52.9 KB LDS -> 3 WG/CU.
// w1r rf-weights in registers; fused GEMM+LN (shuffle rowsum); 2 barriers/tile.
// ---------------------------------------------------------------------------
__global__ __launch_bounds__(256, 3) void edge_kernel(
    const float* __restrict__ h, const float* __restrict__ x,
    const float* __restrict__ preKd, const float* __restrict__ preVd, const float* __restrict__ preXd,
    const float* __restrict__ preKs, const float* __restrict__ preVs, const float* __restrict__ preXs,
    const float* __restrict__ hk_w1, const float* __restrict__ hk_g, const float* __restrict__ hk_be,
    const float* __restrict__ hk_w2, const float* __restrict__ hk_b2,
    const float* __restrict__ hv_w1, const float* __restrict__ hv_g, const float* __restrict__ hv_be,
    const float* __restrict__ hv_w2, const float* __restrict__ hv_b2,
    const float* __restrict__ xv_w1, const float* __restrict__ xv_g, const float* __restrict__ xv_be,
    const float* __restrict__ xv_w2, const float* __restrict__ xv_b2,
    const float* __restrict__ hq_w1, const float* __restrict__ hq_b1, const float* __restrict__ hq_g,
    const float* __restrict__ hq_be, const float* __restrict__ hq_w2, const float* __restrict__ hq_b2,
    const float* __restrict__ no_w1, const float* __restrict__ no_b1, const float* __restrict__ no_g,
    const float* __restrict__ no_be, const float* __restrict__ no_w2, const float* __restrict__ no_b2,
    float* __restrict__ hout, float* __restrict__ xout) {

  __shared__ float smem[13236];
  float* const s_qw    = smem;            // [16][132] proj-q (pass1) / xv_w2^T (pass2b)
  float* const s_logit = smem + 2112;     // [350][16] logits -> alpha
  float* const s_a     = smem + 7712;     // [32][132] activation tile
  float* const s_rfu   = smem + 11936;    // [32][20] rf tile
  float* const s_q     = s_rfu;           //   overlay: [128] (prologue only)
  float* const s_outv  = s_rfu + 128;     //   overlay: [128] (epilogue only)
  float* const s_outx  = s_rfu + 256;     //   overlay: [16][4] (epilogue only)
  float* const s_dist  = smem + 12576;    // [350]
  float* const s_tmp   = smem + 12928;    // [256]
  float* const s_qb    = smem + 13184;    // [16]
  float* const s_mx    = smem + 13200;    // [16]
  float* const s_sum   = smem + 13216;    // [16]
  float* const s_red   = smem + 13232;    // [2]

  const int wg = blockIdx.x;
  const int g = wg / kNL, l = wg % kNL;
  const int lignode = g * kNG + kNP + l;
  const int ligidx = g * kNL + l;
  const int t = threadIdx.x;
  const int c4 = (t & 31) * 4;   // column chunk this thread owns
  const int myp = t >> 5;        // row group (0..7)

  constexpr float kStep = 10.f / 19.f;
  constexpr float kCoeff = -0.5f / (kStep * kStep);

  const float lx0 = x[(size_t)lignode * 3 + 0];
  const float lx1 = x[(size_t)lignode * 3 + 1];
  const float lx2 = x[(size_t)lignode * 3 + 2];

  // ---- P0: stage h[lig]; dist[350] ----
  if (t < 32) *(float4*)&s_tmp[t * 4] = *(const float4*)(h + (size_t)lignode * 128 + t * 4);
  for (int p = t; p < kNP; p += 256) {
    const float* xp = x + (size_t)(g * kNG + p) * 3;
    float r0 = lx0 - xp[0], r1 = lx1 - xp[1], r2 = lx2 - xp[2];
    s_dist[p] = sqrtf(r0 * r0 + r1 * r1 + r2 * r2);
  }
  __syncthreads();

  // ---- q = MLP_hq(h[lig]) ----
  float yq = 0.f;
  if (t < 128) {
    yq = hq_b1[t];
    for (int k = 0; k < 128; ++k) yq += s_tmp[k] * hq_w1[(size_t)k * 128 + t];
    s_a[t] = yq;
  }
  __syncthreads();
  if (t < 64) {
    float v0 = s_a[t], v1 = s_a[t + 64];
    float s = v0 + v1, ss = v0 * v0 + v1 * v1;
#pragma unroll
    for (int off = 32; off; off >>= 1) { s += __shfl_xor(s, off); ss += __shfl_xor(ss, off); }
    if (t == 0) {
      float mu = s / 128.f;
      s_red[0] = mu;
      s_red[1] = rsqrtf(ss / 128.f - mu * mu + 1e-5f);
    }
  }
  __syncthreads();
  if (t < 128) {
    float a = (yq - s_red[0]) * s_red[1] * hq_g[t] + hq_be[t];
    s_tmp[t] = fmaxf(a, 0.f);
  }
  __syncthreads();
  if (t < 128) {
    float qv = hq_b2[t];
    for (int d = 0; d < 128; ++d) qv += s_tmp[d] * hq_w2[(size_t)d * 128 + t];
    s_q[t] = qv;
  }
  __syncthreads();

  // ---- P5: qw[h][d] = (1/sqrt(8)) * sum_j hk_w2[d][h*8+j] q[h*8+j]; qb; rf(tile0) ----
  constexpr float kInvSqrtDH = 0.35355339059327379f;
#pragma unroll
  for (int i = 0; i < 8; ++i) {
    int idx = t + i * 256;
    int hh = idx >> 7, d = idx & 127;
    float4 wa = *(const float4*)(hk_w2 + (size_t)d * 128 + hh * 8);
    float4 wb = *(const float4*)(hk_w2 + (size_t)d * 128 + hh * 8 + 4);
    float v = wa.x * s_q[hh * 8 + 0] + wa.y * s_q[hh * 8 + 1] + wa.z * s_q[hh * 8 + 2] +
              wa.w * s_q[hh * 8 + 3] + wb.x * s_q[hh * 8 + 4] + wb.y * s_q[hh * 8 + 5] +
              wb.z * s_q[hh * 8 + 6] + wb.w * s_q[hh * 8 + 7];
    s_qw[hh * 132 + d] = v * kInvSqrtDH;
  }
  if (t < 16) {
    float v = 0.f;
#pragma unroll
    for (int j = 0; j < 8; ++j) v += hk_b2[t * 8 + j] * s_q[t * 8 + j];
    s_qb[t] = v * kInvSqrtDH;
  }
  for (int o = t; o < TP * 20; o += 256) {
    int p = o / 20;
    float dd = s_dist[p] - (o - p * 20) * kStep;
    s_rfu[o] = __expf(kCoeff * dd * dd);
  }
  __syncthreads();

  // =============== pass 1: logits (hk sweep) ===============
  {
    float4 w1r[20];
#pragma unroll
    for (int gg = 0; gg < 20; ++gg) w1r[gg] = *(const float4*)(hk_w1 + gg * 128 + c4);
    const float4 g4 = *(const float4*)(hk_g + c4);
    const float4 be4 = *(const float4*)(hk_be + c4);
    const float4 pres4 = *(const float4*)(preKs + (size_t)ligidx * 128 + c4);

    for (int tile = 0; tile < NT; ++tile) {
      const int p0 = tile * TP;
      const int np = (350 - p0) < TP ? (350 - p0) : TP;
      // --- fused GEMM + LN ---
      float4 pr[4];
#pragma unroll
      for (int r = 0; r < 4; ++r) {
        int i = myp + r * 8;
        if (i < np) pr[r] = *(const float4*)(preKd + (size_t)(g * kNP + p0 + i) * 128 + c4);
      }
#pragma unroll
      for (int r = 0; r < 4; ++r) {
        int i = myp + r * 8;
        if (i < np) {
          float4 yv;
          yv.x = pres4.x + pr[r].x; yv.y = pres4.y + pr[r].y;
          yv.z = pres4.z + pr[r].z; yv.w = pres4.w + pr[r].w;
#pragma unroll
          for (int gg = 0; gg < 20; ++gg) {
            float rf = s_rfu[i * 20 + gg];
            yv.x += rf * w1r[gg].x; yv.y += rf * w1r[gg].y;
            yv.z += rf * w1r[gg].z; yv.w += rf * w1r[gg].w;
          }
          float s = yv.x + yv.y + yv.z + yv.w;
          float ss = yv.x * yv.x + yv.y * yv.y + yv.z * yv.z + yv.w * yv.w;
#pragma unroll
          for (int m = 16; m; m >>= 1) { s += __shfl_xor(s, m); ss += __shfl_xor(ss, m); }
          float mu = s * (1.f / 128.f);
          float rs = rsqrtf(ss * (1.f / 128.f) - mu * mu + 1e-5f);
          float4 a;
          a.x = fmaxf((yv.x - mu) * rs * g4.x + be4.x, 0.f);
          a.y = fmaxf((yv.y - mu) * rs * g4.y + be4.y, 0.f);
          a.z = fmaxf((yv.z - mu) * rs * g4.z + be4.z, 0.f);
          a.w = fmaxf((yv.w - mu) * rs * g4.w + be4.w, 0.f);
          *(float4*)&s_a[i * 132 + c4] = a;
        }
      }
      __syncthreads();
      // --- logit (p = lane&31, 2 heads) + rf(next tile, wraparound) ---
      {
        const int p = t & 31;
        const int h0 = (t >> 5) * 2, h1 = h0 + 1;
        float f0 = 0.f, f1 = 0.f;
#pragma unroll
        for (int d = 0; d < 128; d += 4) {
          float4 a4 = *(float4*)&s_a[p * 132 + d];
          float4 q0 = *(float4*)&s_qw[h0 * 132 + d];
          float4 q1 = *(float4*)&s_qw[h1 * 132 + d];
          f0 += a4.x * q0.x + a4.y * q0.y + a4.z * q0.z + a4.w * q0.w;
          f1 += a4.x * q1.x + a4.y * q1.y + a4.z * q1.z + a4.w * q1.w;
        }
        if (p < np) {
          s_logit[(p0 + p) * 16 + h0] = f0 + s_qb[h0];
          s_logit[(p0 + p) * 16 + h1] = f1 + s_qb[h1];
        }
        const int nxt = (tile + 1 == NT) ? 0 : tile + 1;
        const int q0p = nxt * TP;
        const int nq = (350 - q0p) < TP ? (350 - q0p) : TP;
        for (int o = t; o < nq * 20; o += 256) {
          int pp = o / 20;
          float dd = s_dist[q0p + pp] - (o - pp * 20) * kStep;
          s_rfu[o] = __expf(kCoeff * dd * dd);
        }
      }
      __syncthreads();
    }
  }

  // =============== softmax over 350 per head ===============
  {
    int hh = t & 15, ck = t >> 4;
    float mx = -1e30f;
    for (int p = ck; p < 350; p += 16) mx = fmaxf(mx, s_logit[p * 16 + hh]);
    s_tmp[t] = mx;
  }
  __syncthreads();
  if (t < 16) {
    float mx = s_tmp[t];
    for (int c = 1; c < 16; ++c) mx = fmaxf(mx, s_tmp[c * 16 + t]);
    s_mx[t] = mx;
  }
  __syncthreads();
  {
    int hh = t & 15, ck = t >> 4;
    float mx = s_mx[hh], sm = 0.f;
    for (int p = ck; p < 350; p += 16) sm += __expf(s_logit[p * 16 + hh] - mx);
    s_tmp[t] = sm;
  }
  __syncthreads();
  if (t < 16) {
    float sm = 0.f;
    for (int c = 0; c < 16; ++c) sm += s_tmp[c * 16 + t];
    s_sum[t] = 1.f / sm;
  }
  __syncthreads();
  for (int o = t; o < 350 * 16; o += 256) {
    int hh = o & 15;
    s_logit[o] = __expf(s_logit[o] - s_mx[hh]) * s_sum[hh];
  }
  // restage: s_qw <- xv_w2^T ; s_qb <- xv_b2  (s_rfu keeps tile0 rf from wraparound)
  for (int o = t; o < 2048; o += 256) {
    int hh = o >> 7, d = o & 127;
    s_qw[hh * 132 + d] = xv_w2[(size_t)d * 16 + hh];
  }
  if (t < 16) s_qb[t] = xv_b2[t];
  __syncthreads();

  // =============== pass 2a: v sweep (hv) ===============
  float accv[8];
#pragma unroll
  for (int i = 0; i < 8; ++i) accv[i] = 0.f;
  const int dd_ = t & 127;
  const int hb8 = (t >> 7) * 8;
  {
    float4 w1r[20];
#pragma unroll
    for (int gg = 0; gg < 20; ++gg) w1r[gg] = *(const float4*)(hv_w1 + gg * 128 + c4);
    const float4 g4 = *(const float4*)(hv_g + c4);
    const float4 be4 = *(const float4*)(hv_be + c4);
    const float4 pres4 = *(const float4*)(preVs + (size_t)ligidx * 128 + c4);

    for (int tile = 0; tile < NT; ++tile) {
      const int p0 = tile * TP;
      const int np = (350 - p0) < TP ? (350 - p0) : TP;
      float4 pr[4];
#pragma unroll
      for (int r = 0; r < 4; ++r) {
        int i = myp + r * 8;
        if (i < np) pr[r] = *(const float4*)(preVd + (size_t)(g * kNP + p0 + i) * 128 + c4);
      }
#pragma unroll
      for (int r = 0; r < 4; ++r) {
        int i = myp + r * 8;
        if (i < np) {
          float4 yv;
          yv.x = pres4.x + pr[r].x; yv.y = pres4.y + pr[r].y;
          yv.z = pres4.z + pr[r].z; yv.w = pres4.w + pr[r].w;
#pragma unroll
          for (int gg = 0; gg < 20; ++gg) {
            float rf = s_rfu[i * 20 + gg];
            yv.x += rf * w1r[gg].x; yv.y += rf * w1r[gg].y;
            yv.z += rf * w1r[gg].z; yv.w += rf * w1r[gg].w;
          }
          float s = yv.x + yv.y + yv.z + yv.w;
          float ss = yv.x * yv.x + yv.y * yv.y + yv.z * yv.z + yv.w * yv.w;
#pragma unroll
          for (int m = 16; m; m >>= 1) { s += __shfl_xor(s, m); ss += __shfl_xor(ss, m); }
          float mu = s * (1.f / 128.f);
          float rs = rsqrtf(ss * (1.f / 128.f) - mu * mu + 1e-5f);
          float4 a;
          a.x = fmaxf((yv.x - mu) * rs * g4.x + be4.x, 0.f);
          a.y = fmaxf((yv.y - mu) * rs * g4.y + be4.y, 0.f);
          a.z = fmaxf((yv.z - mu) * rs * g4.z + be4.z, 0.f);
          a.w = fmaxf((yv.w - mu) * rs * g4.w + be4.w, 0.f);
          *(float4*)&s_a[i * 132 + c4] = a;
        }
      }
      __syncthreads();
      // --- alpha-weighted V accumulation + rf(next) ---
      for (int p = 0; p < np; ++p) {
        float av = s_a[p * 132 + dd_];
        float4 alA = *(float4*)&s_logit[(p0 + p) * 16 + hb8];
        float4 alB = *(float4*)&s_logit[(p0 + p) * 16 + hb8 + 4];
        accv[0] += alA.x * av; accv[1] += alA.y * av;
        accv[2] += alA.z * av; accv[3] += alA.w * av;
        accv[4] += alB.x * av; accv[5] += alB.y * av;
        accv[6] += alB.z * av; accv[7] += alB.w * av;
      }
      {
        const int nxt = (tile + 1 == NT) ? 0 : tile + 1;
        const int q0p = nxt * TP;
        const int nq = (350 - q0p) < TP ? (350 - q0p) : TP;
        for (int o = t; o < nq * 20; o += 256) {
          int pp = o / 20;
          float dd2 = s_dist[q0p + pp] - (o - pp * 20) * kStep;
          s_rfu[o] = __expf(kCoeff * dd2 * dd2);
        }
      }
      __syncthreads();
    }
  }

  // =============== pass 2b: xv sweep ===============
  float ax[6];
#pragma unroll
  for (int i = 0; i < 6; ++i) ax[i] = 0.f;
  {
    float4 w1r[20];
#pragma unroll
    for (int gg = 0; gg < 20; ++gg) w1r[gg] = *(const float4*)(xv_w1 + gg * 128 + c4);
    const float4 g4 = *(const float4*)(xv_g + c4);
    const float4 be4 = *(const float4*)(xv_be + c4);
    const float4 pres4 = *(const float4*)(preXs + (size_t)ligidx * 128 + c4);
    const int p_ = t & 31;
    const int h0 = (t >> 5) * 2, h1 = h0 + 1;

    for (int tile = 0; tile < NT; ++tile) {
      const int p0 = tile * TP;
      const int np = (350 - p0) < TP ? (350 - p0) : TP;
      float4 pr[4];
#pragma unroll
      for (int r = 0; r < 4; ++r) {
        int i = myp + r * 8;
        if (i < np) pr[r] = *(const float4*)(preXd + (size_t)(g * kNP + p0 + i) * 128 + c4);
      }
#pragma unroll
      for (int r = 0; r < 4; ++r) {
        int i = myp + r * 8;
        if (i < np) {
          float4 yv;
          yv.x = pres4.x + pr[r].x; yv.y = pres4.y + pr[r].y;
          yv.z = pres4.z + pr[r].z; yv.w = pres4.w + pr[r].w;
#pragma unroll
          for (int gg = 0; gg < 20; ++gg) {
            float rf = s_rfu[i * 20 + gg];
            yv.x += rf * w1r[gg].x; yv.y += rf * w1r[gg].y;
            yv.z += rf * w1r[gg].z; yv.w += rf * w1r[gg].w;
          }
          float s = yv.x + yv.y + yv.z + yv.w;
          float ss = yv.x * yv.x + yv.y * yv.y + yv.z * yv.z + yv.w * yv.w;
#pragma unroll
          for (int m = 16; m; m >>= 1) { s += __shfl_xor(s, m); ss += __shfl_xor(ss, m); }
          float mu = s * (1.f / 128.f);
          float rs = rsqrtf(ss * (1.f / 128.f) - mu * mu + 1e-5f);
          float4 a;
          a.x = fmaxf((yv.x - mu) * rs * g4.x + be4.x, 0.f);
          a.y = fmaxf((yv.y - mu) * rs * g4.y + be4.y, 0.f);
          a.z = fmaxf((yv.z - mu) * rs * g4.z + be4.z, 0.f);
          a.w = fmaxf((yv.w - mu) * rs * g4.w + be4.w, 0.f);
          *(float4*)&s_a[i * 132 + c4] = a;
        }
      }
      __syncthreads();
      // --- xv projection + alpha + rel_x, half-wave shuffle reduce ---
      {
        float f0 = 0.f, f1 = 0.f;
#pragma unroll
        for (int d = 0; d < 128; d += 4) {
          float4 a4 = *(float4*)&s_a[p_ * 132 + d];
          float4 q0 = *(float4*)&s_qw[h0 * 132 + d];
          float4 q1 = *(float4*)&s_qw[h1 * 132 + d];
          f0 += a4.x * q0.x + a4.y * q0.y + a4.z * q0.z + a4.w * q0.w;
          f1 += a4.x * q1.x + a4.y * q1.y + a4.z * q1.z + a4.w * q1.w;
        }
        float w0 = 0.f, w1 = 0.f, r0 = 0.f, r1 = 0.f, r2 = 0.f;
        if (p_ < np) {
          int pg = p0 + p_;
          w0 = s_logit[pg * 16 + h0] * (f0 + s_qb[h0]);
          w1 = s_logit[pg * 16 + h1] * (f1 + s_qb[h1]);
          const float* xp = x + (size_t)(g * kNG + pg) * 3;
          r0 = lx0 - xp[0]; r1 = lx1 - xp[1]; r2 = lx2 - xp[2];
        }
        float p00 = w0 * r0, p01 = w0 * r1, p02 = w0 * r2;
        float p10 = w1 * r0, p11 = w1 * r1, p12 = w1 * r2;
#pragma unroll
        for (int m = 16; m; m >>= 1) {
          p00 += __shfl_xor(p00, m); p01 += __shfl_xor(p01, m); p02 += __shfl_xor(p02, m);
          p10 += __shfl_xor(p10, m); p11 += __shfl_xor(p11, m); p12 += __shfl_xor(p12, m);
        }
        ax[0] += p00; ax[1] += p01; ax[2] += p02;
        ax[3] += p10; ax[4] += p11; ax[5] += p12;
      }
      {
        const int nxt = (tile + 1 == NT) ? 0 : tile + 1;
        const int q0p = nxt * TP;
        const int nq = (350 - q0p) < TP ? (350 - q0p) : TP;
        for (int o = t; o < nq * 20; o += 256) {
          int pp = o / 20;
          float dd2 = s_dist[q0p + pp] - (o - pp * 20) * kStep;
          s_rfu[o] = __expf(kCoeff * dd2 * dd2);
        }
      }
      __syncthreads();
    }
  }

  // =============== epilogue ===============
#pragma unroll
  for (int i = 0; i < 8; ++i) s_a[(hb8 + i) * 132 + dd_] = accv[i];
  {
    const int h0 = (t >> 5) * 2;
    if ((t & 31) == 0) {
      s_outx[h0 * 4 + 0] = ax[0]; s_outx[h0 * 4 + 1] = ax[1]; s_outx[h0 * 4 + 2] = ax[2];
      s_outx[(h0 + 1) * 4 + 0] = ax[3]; s_outx[(h0 + 1) * 4 + 1] = ax[4];
      s_outx[(h0 + 1) * 4 + 2] = ax[5];
    }
  }
  __syncthreads();

  if (t < 128) {
    float o = hv_b2[t];
    const int hh = t >> 3;
    for (int d = 0; d < 128; ++d) o += s_a[hh * 132 + d] * hv_w2[(size_t)d * 128 + t];
    s_outv[t] = o;
  }
  if (t >= 128 && t < 131) {
    int c = t - 128;
    float sm = 0.f;
#pragma unroll
    for (int hh = 0; hh < 16; ++hh) sm += s_outx[hh * 4 + c];
    xout[(size_t)lignode * 3 + c] = x[(size_t)lignode * 3 + c] + sm * (1.f / 16.f);
  }
  __syncthreads();
  float yn = 0.f;
  if (t < 128) {
    yn = no_b1[t];
    for (int i = 0; i < 128; ++i) yn += s_outv[i] * no_w1[(size_t)i * 128 + t];
    const float* h1 = h + 128;  // h row 1 (mask_ligand int gather, faithful to source)
    for (int i = 0; i < 128; ++i) yn += h1[i] * no_w1[(size_t)(128 + i) * 128 + t];
    s_tmp[t] = yn;
  }
  __syncthreads();
  if (t < 64) {
    float v0 = s_tmp[t], v1 = s_tmp[t + 64];
    float s = v0 + v1, ss = v0 * v0 + v1 * v1;
#pragma unroll
    for (int off = 32; off; off >>= 1) { s += __shfl_xor(s, off); ss += __shfl_xor(ss, off); }
    if (t == 0) {
      float mu = s / 128.f;
      s_red[0] = mu;
      s_red[1] = rsqrtf(ss / 128.f - mu * mu + 1e-5f);
    }
  }
  __syncthreads();
  if (t < 128) {
    float a = (yn - s_red[0]) * s_red[1] * no_g[t] + no_be[t];
    s_outv[t] = fmaxf(a, 0.f);
  }
  __syncthreads();
  if (t < 128) {
    float o = no_b2[t];
    for (int d = 0; d < 128; ++d) o += s_outv[d] * no_w2[(size_t)d * 128 + t];
    hout[(size_t)lignode * 128 + t] = o + h[(size_t)lignode * 128 + t];
  }
}

// ---------------------------------------------------------------------------
extern "C" void kernel_launch(void* const* d_in, const int* in_sizes, int n_in,
                              void* d_out, int out_size, void* d_ws, size_t ws_size,
                              hipStream_t stream) {
  (void)in_sizes; (void)n_in; (void)out_size; (void)ws_size;
  const float* h = (const float*)d_in[0];
  const float* x = (const float*)d_in[1];
  const float* hk_w1 = (const float*)d_in[5];
  const float* hk_b1 = (const float*)d_in[6];
  const float* hk_g  = (const float*)d_in[7];
  const float* hk_be = (const float*)d_in[8];
  const float* hk_w2 = (const float*)d_in[9];
  const float* hk_b2 = (const float*)d_in[10];
  const float* hv_w1 = (const float*)d_in[11];
  const float* hv_b1 = (const float*)d_in[12];
  const float* hv_g  = (const float*)d_in[13];
  const float* hv_be = (const float*)d_in[14];
  const float* hv_w2 = (const float*)d_in[15];
  const float* hv_b2 = (const float*)d_in[16];
  const float* xv_w1 = (const float*)d_in[17];
  const float* xv_b1 = (const float*)d_in[18];
  const float* xv_g  = (const float*)d_in[19];
  const float* xv_be = (const float*)d_in[20];
  const float* xv_w2 = (const float*)d_in[21];
  const float* xv_b2 = (const float*)d_in[22];
  const float* hq_w1 = (const float*)d_in[23];
  const float* hq_b1 = (const float*)d_in[24];
  const float* hq_g  = (const float*)d_in[25];
  const float* hq_be = (const float*)d_in[26];
  const float* hq_w2 = (const float*)d_in[27];
  const float* hq_b2 = (const float*)d_in[28];
  const float* no_w1 = (const float*)d_in[29];
  const float* no_b1 = (const float*)d_in[30];
  const float* no_g  = (const float*)d_in[31];
  const float* no_be = (const float*)d_in[32];
  const float* no_w2 = (const float*)d_in[33];
  const float* no_b2 = (const float*)d_in[34];

  float* ws = (float*)d_ws;
  float* preKd = ws;
  float* preVd = preKd + (size_t)kNPROT * 128;
  float* preXd = preVd + (size_t)kNPROT * 128;
  float* preKs = preXd + (size_t)kNPROT * 128;
  float* preVs = preKs + (size_t)kNLIG * 128;
  float* preXs = preVs + (size_t)kNLIG * 128;
  float* cvec  = preXs + (size_t)kNLIG * 128;

  float* hout = (float*)d_out;
  float* xout = hout + (size_t)kN * 128;

  pre_kernel<<<dim3(190, 3), dim3(256), 0, stream>>>(
      h, hk_w1, hk_b1, hv_w1, hv_b1, xv_w1, xv_b1,
      preKd, preVd, preXd, preKs, preVs, preXs);
  cvec_kernel<<<dim3(1), dim3(128), 0, stream>>>(
      h, no_w1, no_b1, no_g, no_be, no_w2, no_b2, cvec);
  edge_kernel<<<dim3(960), dim3(256), 0, stream>>>(
      h, x, preKd, preVd, preXd, preKs, preVs, preXs,
      hk_w1, hk_g, hk_be, hk_w2, hk_b2,
      hv_w1, hv_g, hv_be, hv_w2, hv_b2,
      xv_w1, xv_g, xv_be, xv_w2, xv_b2,
      hq_w1, hq_b1, hq_g, hq_be, hq_w2, hq_b2,
      no_w1, no_b1, no_g, no_be, no_w2, no_b2,
      hout, xout);
  prot_kernel<<<dim3(1400), dim3(256), 0, stream>>>(h, x, cvec, hout, xout);
}

// Round 10
// 694.654 us; speedup vs baseline: 1.5016x; 1.5016x over previous
//
#include <hip/hip_runtime.h>
#include <math.h>

namespace {
constexpr int kB = 32;
constexpr int kNP = 350;
constexpr int kNL = 30;
constexpr int kNG = 380;
constexpr int kN = kB * kNG;      // 12160
constexpr int kG = 20;
constexpr int kNPROT = kB * kNP;  // 11200
constexpr int kNLIG = kB * kNL;   // 960
constexpr int TP = 32;            // protein tile
constexpr int NT = 11;            // tiles (10*32 + 30)
}  // namespace

// ---------------------------------------------------------------------------
// Kernel A: node-level precompute (unchanged — verified R2).
// ---------------------------------------------------------------------------
__global__ __launch_bounds__(256) void pre_kernel(
    const float* __restrict__ h,
    const float* __restrict__ wk1, const float* __restrict__ bk1,
    const float* __restrict__ wv1, const float* __restrict__ bv1,
    const float* __restrict__ wx1, const float* __restrict__ bx1,
    float* __restrict__ outKd, float* __restrict__ outVd, float* __restrict__ outXd,
    float* __restrict__ outKs, float* __restrict__ outVs, float* __restrict__ outXs) {
  const int m = blockIdx.y;
  const float* w1 = (m == 0) ? wk1 : (m == 1) ? wv1 : wx1;
  const float* b1 = (m == 0) ? bk1 : (m == 1) ? bv1 : bx1;
  const bool isProt = (blockIdx.x < 175);
  const int rbase = isProt ? blockIdx.x * 64 : (blockIdx.x - 175) * 64;
  float* outArr = isProt ? ((m == 0) ? outKd : (m == 1) ? outVd : outXd)
                         : ((m == 0) ? outKs : (m == 1) ? outVs : outXs);
  const float* wb = w1 + (isProt ? 20 * 128 : 148 * 128);

  __shared__ float sh[64 * 132];
  const int t = threadIdx.x;
#pragma unroll
  for (int j = 0; j < 8; ++j) {
    int flat = t + j * 256;
    int row = flat >> 5;
    int col = (flat & 31) * 4;
    int r = rbase + row;
    int node;
    if (isProt) node = (r / kNP) * kNG + (r % kNP);
    else        node = (r / kNL) * kNG + kNP + (r % kNL);
    *(float4*)&sh[row * 132 + col] = *(const float4*)(h + (size_t)node * 128 + col);
  }
  __syncthreads();

  const int dcol = (t & 31) * 4;
  const int rrow = (t >> 5) * 8;
  float4 acc[8];
#pragma unroll
  for (int i = 0; i < 8; ++i) acc[i] = make_float4(0.f, 0.f, 0.f, 0.f);

  for (int k = 0; k < 128; k += 4) {
    float4 a4[8];
#pragma unroll
    for (int i = 0; i < 8; ++i) a4[i] = *(float4*)&sh[(rrow + i) * 132 + k];
#pragma unroll
    for (int kk = 0; kk < 4; ++kk) {
      float4 w4 = *(const float4*)(wb + (size_t)(k + kk) * 128 + dcol);
#pragma unroll
      for (int i = 0; i < 8; ++i) {
        float a = (kk == 0) ? a4[i].x : (kk == 1) ? a4[i].y : (kk == 2) ? a4[i].z : a4[i].w;
        acc[i].x += a * w4.x; acc[i].y += a * w4.y;
        acc[i].z += a * w4.z; acc[i].w += a * w4.w;
      }
    }
  }
  float4 bias = make_float4(0.f, 0.f, 0.f, 0.f);
  if (!isProt) bias = *(const float4*)(b1 + dcol);
#pragma unroll
  for (int i = 0; i < 8; ++i) {
    float4 o = acc[i];
    o.x += bias.x; o.y += bias.y; o.z += bias.z; o.w += bias.w;
    *(float4*)(outArr + (size_t)(rbase + rrow + i) * 128 + dcol) = o;
  }
}

// ---------------------------------------------------------------------------
// Kernel cvec (unchanged).
// ---------------------------------------------------------------------------
__global__ __launch_bounds__(128) void cvec_kernel(
    const float* __restrict__ h,
    const float* __restrict__ no_w1, const float* __restrict__ no_b1,
    const float* __restrict__ no_g, const float* __restrict__ no_be,
    const float* __restrict__ no_w2, const float* __restrict__ no_b2,
    float* __restrict__ cvec) {
  __shared__ float sy[128];
  __shared__ float sa[128];
  __shared__ float red[2];
  const int d = threadIdx.x;
  float y = no_b1[d];
  for (int i = 0; i < 128; ++i) y += h[i] * no_w1[(size_t)(128 + i) * 128 + d];
  sy[d] = y;
  __syncthreads();
  if (d == 0) {
    float s = 0.f, ss = 0.f;
    for (int i = 0; i < 128; ++i) { s += sy[i]; ss += sy[i] * sy[i]; }
    float mu = s / 128.f;
    red[0] = mu;
    red[1] = rsqrtf(ss / 128.f - mu * mu + 1e-5f);
  }
  __syncthreads();
  float a = (y - red[0]) * red[1] * no_g[d] + no_be[d];
  sa[d] = fmaxf(a, 0.f);
  __syncthreads();
  float o = no_b2[d];
  for (int i = 0; i < 128; ++i) o += sa[i] * no_w2[(size_t)i * 128 + d];
  cvec[d] = o;
}

// ---------------------------------------------------------------------------
// Kernel D: protein nodes (unchanged).
// ---------------------------------------------------------------------------
__global__ __launch_bounds__(256) void prot_kernel(
    const float* __restrict__ h, const float* __restrict__ x,
    const float* __restrict__ cvec, float* __restrict__ hout, float* __restrict__ xout) {
  int idx = blockIdx.x * 256 + threadIdx.x;
  if (idx < kNPROT * 32) {
    int r = idx >> 5, c4 = (idx & 31) * 4;
    int node = (r / kNP) * kNG + (r % kNP);
    float4 hv = *(const float4*)(h + (size_t)node * 128 + c4);
    float4 cv = *(const float4*)(cvec + c4);
    *(float4*)(hout + (size_t)node * 128 + c4) =
        make_float4(hv.x + cv.x, hv.y + cv.y, hv.z + cv.z, hv.w + cv.w);
  }
  if (idx < kNPROT * 3) {
    int r = idx / 3, c = idx % 3;
    int node = (r / kNP) * kNG + (r % kNP);
    xout[(size_t)node * 3 + c] = x[(size_t)node * 3 + c];
  }
}

// ---------------------------------------------------------------------------
// Weight block held in 20 NAMED float4 members (no array -> no runtime
// indexing -> SROA keeps all 80 floats in VGPRs; R6's float4[20] array was
// demoted to scratch: FETCH 73 MB -> 1.46 GB). Plain C++, no macros (R8's
// macro version was corrupted in transit and failed to compile).
// ---------------------------------------------------------------------------
struct W20 {
  float4 a0, a1, a2, a3, a4, a5, a6, a7, a8, a9;
  float4 a10, a11, a12, a13, a14, a15, a16, a17, a18, a19;
};

__device__ __forceinline__ W20 load_w20(const float* __restrict__ W, int c4) {
  W20 r;
  r.a0  = *(const float4*)(W + 0 * 128 + c4);
  r.a1  = *(const float4*)(W + 1 * 128 + c4);
  r.a2  = *(const float4*)(W + 2 * 128 + c4);
  r.a3  = *(const float4*)(W + 3 * 128 + c4);
  r.a4  = *(const float4*)(W + 4 * 128 + c4);
  r.a5  = *(const float4*)(W + 5 * 128 + c4);
  r.a6  = *(const float4*)(W + 6 * 128 + c4);
  r.a7  = *(const float4*)(W + 7 * 128 + c4);
  r.a8  = *(const float4*)(W + 8 * 128 + c4);
  r.a9  = *(const float4*)(W + 9 * 128 + c4);
  r.a10 = *(const float4*)(W + 10 * 128 + c4);
  r.a11 = *(const float4*)(W + 11 * 128 + c4);
  r.a12 = *(const float4*)(W + 12 * 128 + c4);
  r.a13 = *(const float4*)(W + 13 * 128 + c4);
  r.a14 = *(const float4*)(W + 14 * 128 + c4);
  r.a15 = *(const float4*)(W + 15 * 128 + c4);
  r.a16 = *(const float4*)(W + 16 * 128 + c4);
  r.a17 = *(const float4*)(W + 17 * 128 + c4);
  r.a18 = *(const float4*)(W + 18 * 128 + c4);
  r.a19 = *(const float4*)(W + 19 * 128 + c4);
  return r;
}

// yv += rf_row(20) @ W(20x4); rf row read as 5x ds_read_b128 (80B, 16B-aligned).
__device__ __forceinline__ float4 gemm20(const W20& w, const float* rfp, float4 yv) {
  const float4 ra = *(const float4*)(rfp + 0);
  const float4 rb = *(const float4*)(rfp + 4);
  const float4 rc = *(const float4*)(rfp + 8);
  const float4 rd = *(const float4*)(rfp + 12);
  const float4 re = *(const float4*)(rfp + 16);
  yv.x += ra.x * w.a0.x;  yv.y += ra.x * w.a0.y;  yv.z += ra.x * w.a0.z;  yv.w += ra.x * w.a0.w;
  yv.x += ra.y * w.a1.x;  yv.y += ra.y * w.a1.y;  yv.z += ra.y * w.a1.z;  yv.w += ra.y * w.a1.w;
  yv.x += ra.z * w.a2.x;  yv.y += ra.z * w.a2.y;  yv.z += ra.z * w.a2.z;  yv.w += ra.z * w.a2.w;
  yv.x += ra.w * w.a3.x;  yv.y += ra.w * w.a3.y;  yv.z += ra.w * w.a3.z;  yv.w += ra.w * w.a3.w;
  yv.x += rb.x * w.a4.x;  yv.y += rb.x * w.a4.y;  yv.z += rb.x * w.a4.z;  yv.w += rb.x * w.a4.w;
  yv.x += rb.y * w.a5.x;  yv.y += rb.y * w.a5.y;  yv.z += rb.y * w.a5.z;  yv.w += rb.y * w.a5.w;
  yv.x += rb.z * w.a6.x;  yv.y += rb.z * w.a6.y;  yv.z += rb.z * w.a6.z;  yv.w += rb.z * w.a6.w;
  yv.x += rb.w * w.a7.x;  yv.y += rb.w * w.a7.y;  yv.z += rb.w * w.a7.z;  yv.w += rb.w * w.a7.w;
  yv.x += rc.x * w.a8.x;  yv.y += rc.x * w.a8.y;  yv.z += rc.x * w.a8.z;  yv.w += rc.x * w.a8.w;
  yv.x += rc.y * w.a9.x;  yv.y += rc.y * w.a9.y;  yv.z += rc.y * w.a9.z;  yv.w += rc.y * w.a9.w;
  yv.x += rc.z * w.a10.x; yv.y += rc.z * w.a10.y; yv.z += rc.z * w.a10.z; yv.w += rc.z * w.a10.w;
  yv.x += rc.w * w.a11.x; yv.y += rc.w * w.a11.y; yv.z += rc.w * w.a11.z; yv.w += rc.w * w.a11.w;
  yv.x += rd.x * w.a12.x; yv.y += rd.x * w.a12.y; yv.z += rd.x * w.a12.z; yv.w += rd.x * w.a12.w;
  yv.x += rd.y * w.a13.x; yv.y += rd.y * w.a13.y; yv.z += rd.y * w.a13.z; yv.w += rd.y * w.a13.w;
  yv.x += rd.z * w.a14.x; yv.y += rd.z * w.a14.y; yv.z += rd.z * w.a14.z; yv.w += rd.z * w.a14.w;
  yv.x += rd.w * w.a15.x; yv.y += rd.w * w.a15.y; yv.z += rd.w * w.a15.z; yv.w += rd.w * w.a15.w;
  yv.x += re.x * w.a16.x; yv.y += re.x * w.a16.y; yv.z += re.x * w.a16.z; yv.w += re.x * w.a16.w;
  yv.x += re.y * w.a17.x; yv.y += re.y * w.a17.y; yv.z += re.y * w.a17.z; yv.w += re.y * w.a17.w;
  yv.x += re.z * w.a18.x; yv.y += re.z * w.a18.y; yv.z += re.z * w.a18.z; yv.w += re.z * w.a18.w;
  yv.x += re.w * w.a19.x; yv.y += re.w * w.a19.y; yv.z += re.w * w.a19.z; yv.w += re.w * w.a19.w;
  return yv;
}

// LayerNorm(row of 128 spread over 32 lanes x float4) + ReLU, store to LDS.
// Shuffle masks <=16 stay within the 32-lane half; caller guard is uniform
// per 32-lane group (depends on myp only).
__device__ __forceinline__ void ln_relu_store(float4 yv, float4 g4, float4 be4, float* dst) {
  float s = yv.x + yv.y + yv.z + yv.w;
  float ss = yv.x * yv.x + yv.y * yv.y + yv.z * yv.z + yv.w * yv.w;
  for (int m = 16; m; m >>= 1) { s += __shfl_xor(s, m); ss += __shfl_xor(ss, m); }
  float mu = s * (1.f / 128.f);
  float rs = rsqrtf(ss * (1.f / 128.f) - mu * mu + 1e-5f);
  float4 a;
  a.x = fmaxf((yv.x - mu) * rs * g4.x + be4.x, 0.f);
  a.y = fmaxf((yv.y - mu) * rs * g4.y + be4.y, 0.f);
  a.z = fmaxf((yv.z - mu) * rs * g4.z + be4.z, 0.f);
  a.w = fmaxf((yv.w - mu) * rs * g4.w + be4.w, 0.f);
  *(float4*)dst = a;
}

__device__ __forceinline__ float4 addf4(float4 a, float4 b) {
  return make_float4(a.x + b.x, a.y + b.y, a.z + b.z, a.w + b.w);
}

// ---------------------------------------------------------------------------
// Kernel B: one WG per ligand. 52.9 KB LDS. launch_bounds(256,2): 256-VGPR
// budget so the 80 weight registers fit with slack (R6's (256,3) budget of
// 168 forced the spill -> scratch -> HBM-bound).
// ---------------------------------------------------------------------------
__global__ __launch_bounds__(256, 2) void edge_kernel(
    const float* __restrict__ h, const float* __restrict__ x,
    const float* __restrict__ preKd, const float* __restrict__ preVd, const float* __restrict__ preXd,
    const float* __restrict__ preKs, const float* __restrict__ preVs, const float* __restrict__ preXs,
    const float* __restrict__ hk_w1, const float* __restrict__ hk_g, const float* __restrict__ hk_be,
    const float* __restrict__ hk_w2, const float* __restrict__ hk_b2,
    const float* __restrict__ hv_w1, const float* __restrict__ hv_g, const float* __restrict__ hv_be,
    const float* __restrict__ hv_w2, const float* __restrict__ hv_b2,
    const float* __restrict__ xv_w1, const float* __restrict__ xv_g, const float* __restrict__ xv_be,
    const float* __restrict__ xv_w2, const float* __restrict__ xv_b2,
    const float* __restrict__ hq_w1, const float* __restrict__ hq_b1, const float* __restrict__ hq_g,
    const float* __restrict__ hq_be, const float* __restrict__ hq_w2, const float* __restrict__ hq_b2,
    const float* __restrict__ no_w1, const float* __restrict__ no_b1, const float* __restrict__ no_g,
    const float* __restrict__ no_be, const float* __restrict__ no_w2, const float* __restrict__ no_b2,
    float* __restrict__ hout, float* __restrict__ xout) {

  __shared__ float smem[13236];
  float* const s_qw    = smem;            // [16][132] proj-q (pass1) / xv_w2^T (pass2b)
  float* const s_logit = smem + 2112;     // [350][16] logits -> alpha
  float* const s_a     = smem + 7712;     // [32][132] activation tile
  float* const s_rfu   = smem + 11936;    // [32][20] rf tile
  float* const s_q     = s_rfu;           //   overlay: [128] (prologue only)
  float* const s_outv  = s_rfu + 128;     //   overlay: [128] (epilogue only)
  float* const s_outx  = s_rfu + 256;     //   overlay: [16][4] (epilogue only)
  float* const s_dist  = smem + 12576;    // [350]
  float* const s_tmp   = smem + 12928;    // [256]
  float* const s_qb    = smem + 13184;    // [16]
  float* const s_mx    = smem + 13200;    // [16]
  float* const s_sum   = smem + 13216;    // [16]
  float* const s_red   = smem + 13232;    // [2]

  const int wg = blockIdx.x;
  const int g = wg / kNL, l = wg % kNL;
  const int lignode = g * kNG + kNP + l;
  const int ligidx = g * kNL + l;
  const int t = threadIdx.x;
  const int c4 = (t & 31) * 4;   // column chunk this thread owns
  const int myp = t >> 5;        // row group (0..7)

  constexpr float kStep = 10.f / 19.f;
  constexpr float kCoeff = -0.5f / (kStep * kStep);

  const float lx0 = x[(size_t)lignode * 3 + 0];
  const float lx1 = x[(size_t)lignode * 3 + 1];
  const float lx2 = x[(size_t)lignode * 3 + 2];

  // ---- P0: stage h[lig]; dist[350] ----
  if (t < 32) *(float4*)&s_tmp[t * 4] = *(const float4*)(h + (size_t)lignode * 128 + t * 4);
  for (int p = t; p < kNP; p += 256) {
    const float* xp = x + (size_t)(g * kNG + p) * 3;
    float r0 = lx0 - xp[0], r1 = lx1 - xp[1], r2 = lx2 - xp[2];
    s_dist[p] = sqrtf(r0 * r0 + r1 * r1 + r2 * r2);
  }
  __syncthreads();

  // ---- q = MLP_hq(h[lig]) ----
  float yq = 0.f;
  if (t < 128) {
    yq = hq_b1[t];
    for (int k = 0; k < 128; ++k) yq += s_tmp[k] * hq_w1[(size_t)k * 128 + t];
    s_a[t] = yq;
  }
  __syncthreads();
  if (t < 64) {
    float v0 = s_a[t], v1 = s_a[t + 64];
    float s = v0 + v1, ss = v0 * v0 + v1 * v1;
#pragma unroll
    for (int off = 32; off; off >>= 1) { s += __shfl_xor(s, off); ss += __shfl_xor(ss, off); }
    if (t == 0) {
      float mu = s / 128.f;
      s_red[0] = mu;
      s_red[1] = rsqrtf(ss / 128.f - mu * mu + 1e-5f);
    }
  }
  __syncthreads();
  if (t < 128) {
    float a = (yq - s_red[0]) * s_red[1] * hq_g[t] + hq_be[t];
    s_tmp[t] = fmaxf(a, 0.f);
  }
  __syncthreads();
  if (t < 128) {
    float qv = hq_b2[t];
    for (int d = 0; d < 128; ++d) qv += s_tmp[d] * hq_w2[(size_t)d * 128 + t];
    s_q[t] = qv;
  }
  __syncthreads();

  // ---- qw[h][d] = (1/sqrt(8)) * sum_j hk_w2[d][h*8+j] q[h*8+j]; qb; rf(tile0) ----
  constexpr float kInvSqrtDH = 0.35355339059327379f;
#pragma unroll
  for (int i = 0; i < 8; ++i) {
    int idx = t + i * 256;
    int hh = idx >> 7, d = idx & 127;
    float4 wa = *(const float4*)(hk_w2 + (size_t)d * 128 + hh * 8);
    float4 wb = *(const float4*)(hk_w2 + (size_t)d * 128 + hh * 8 + 4);
    float v = wa.x * s_q[hh * 8 + 0] + wa.y * s_q[hh * 8 + 1] + wa.z * s_q[hh * 8 + 2] +
              wa.w * s_q[hh * 8 + 3] + wb.x * s_q[hh * 8 + 4] + wb.y * s_q[hh * 8 + 5] +
              wb.z * s_q[hh * 8 + 6] + wb.w * s_q[hh * 8 + 7];
    s_qw[hh * 132 + d] = v * kInvSqrtDH;
  }
  if (t < 16) {
    float v = 0.f;
#pragma unroll
    for (int j = 0; j < 8; ++j) v += hk_b2[t * 8 + j] * s_q[t * 8 + j];
    s_qb[t] = v * kInvSqrtDH;
  }
  for (int o = t; o < TP * 20; o += 256) {
    int p = o / 20;
    float dd = s_dist[p] - (o - p * 20) * kStep;
    s_rfu[o] = __expf(kCoeff * dd * dd);
  }
  __syncthreads();

  // =============== pass 1: logits (hk sweep) ===============
  {
    const W20 w = load_w20(hk_w1, c4);
    const float4 g4 = *(const float4*)(hk_g + c4);
    const float4 be4 = *(const float4*)(hk_be + c4);
    const float4 pres4 = *(const float4*)(preKs + (size_t)ligidx * 128 + c4);

    for (int tile = 0; tile < NT; ++tile) {
      const int p0 = tile * TP;
      const int np = (350 - p0) < TP ? (350 - p0) : TP;
      const int i0 = myp, i1 = myp + 8, i2 = myp + 16, i3 = myp + 24;
      float4 pr0, pr1, pr2, pr3;
      const float* base = preKd + (size_t)(g * kNP + p0) * 128 + c4;
      pr0 = *(const float4*)(base + (size_t)i0 * 128);
      pr1 = *(const float4*)(base + (size_t)i1 * 128);
      pr2 = *(const float4*)(base + (size_t)i2 * 128);
      if (i3 < np) pr3 = *(const float4*)(base + (size_t)i3 * 128);
      ln_relu_store(gemm20(w, &s_rfu[i0 * 20], addf4(pres4, pr0)), g4, be4, &s_a[i0 * 132 + c4]);
      ln_relu_store(gemm20(w, &s_rfu[i1 * 20], addf4(pres4, pr1)), g4, be4, &s_a[i1 * 132 + c4]);
      ln_relu_store(gemm20(w, &s_rfu[i2 * 20], addf4(pres4, pr2)), g4, be4, &s_a[i2 * 132 + c4]);
      if (i3 < np)
        ln_relu_store(gemm20(w, &s_rfu[i3 * 20], addf4(pres4, pr3)), g4, be4, &s_a[i3 * 132 + c4]);
      __syncthreads();
      // --- logit (p = lane&31, 2 heads) + rf(next tile, wraparound) ---
      {
        const int p = t & 31;
        const int h0 = (t >> 5) * 2, h1 = h0 + 1;
        float f0 = 0.f, f1 = 0.f;
#pragma unroll
        for (int d = 0; d < 128; d += 4) {
          float4 a4 = *(float4*)&s_a[p * 132 + d];
          float4 q0 = *(float4*)&s_qw[h0 * 132 + d];
          float4 q1 = *(float4*)&s_qw[h1 * 132 + d];
          f0 += a4.x * q0.x + a4.y * q0.y + a4.z * q0.z + a4.w * q0.w;
          f1 += a4.x * q1.x + a4.y * q1.y + a4.z * q1.z + a4.w * q1.w;
        }
        if (p < np) {
          s_logit[(p0 + p) * 16 + h0] = f0 + s_qb[h0];
          s_logit[(p0 + p) * 16 + h1] = f1 + s_qb[h1];
        }
        const int nxt = (tile + 1 == NT) ? 0 : tile + 1;
        const int q0p = nxt * TP;
        const int nq = (350 - q0p) < TP ? (350 - q0p) : TP;
        for (int o = t; o < nq * 20; o += 256) {
          int pp = o / 20;
          float dd = s_dist[q0p + pp] - (o - pp * 20) * kStep;
          s_rfu[o] = __expf(kCoeff * dd * dd);
        }
      }
      __syncthreads();
    }
  }

  // =============== softmax over 350 per head ===============
  {
    int hh = t & 15, ck = t >> 4;
    float mx = -1e30f;
    for (int p = ck; p < 350; p += 16) mx = fmaxf(mx, s_logit[p * 16 + hh]);
    s_tmp[t] = mx;
  }
  __syncthreads();
  if (t < 16) {
    float mx = s_tmp[t];
    for (int c = 1; c < 16; ++c) mx = fmaxf(mx, s_tmp[c * 16 + t]);
    s_mx[t] = mx;
  }
  __syncthreads();
  {
    int hh = t & 15, ck = t >> 4;
    float mx = s_mx[hh], sm = 0.f;
    for (int p = ck; p < 350; p += 16) sm += __expf(s_logit[p * 16 + hh] - mx);
    s_tmp[t] = sm;
  }
  __syncthreads();
  if (t < 16) {
    float sm = 0.f;
    for (int c = 0; c < 16; ++c) sm += s_tmp[c * 16 + t];
    s_sum[t] = 1.f / sm;
  }
  __syncthreads();
  for (int o = t; o < 350 * 16; o += 256) {
    int hh = o & 15;
    s_logit[o] = __expf(s_logit[o] - s_mx[hh]) * s_sum[hh];
  }
  // restage: s_qw <- xv_w2^T ; s_qb <- xv_b2  (s_rfu keeps tile0 rf from wraparound)
  for (int o = t; o < 2048; o += 256) {
    int hh = o >> 7, d = o & 127;
    s_qw[hh * 132 + d] = xv_w2[(size_t)d * 16 + hh];
  }
  if (t < 16) s_qb[t] = xv_b2[t];
  __syncthreads();

  // =============== pass 2a: v sweep (hv) ===============
  float accv0 = 0.f, accv1 = 0.f, accv2 = 0.f, accv3 = 0.f;
  float accv4 = 0.f, accv5 = 0.f, accv6 = 0.f, accv7 = 0.f;
  const int dd_ = t & 127;
  const int hb8 = (t >> 7) * 8;
  {
    const W20 w = load_w20(hv_w1, c4);
    const float4 g4 = *(const float4*)(hv_g + c4);
    const float4 be4 = *(const float4*)(hv_be + c4);
    const float4 pres4 = *(const float4*)(preVs + (size_t)ligidx * 128 + c4);

    for (int tile = 0; tile < NT; ++tile) {
      const int p0 = tile * TP;
      const int np = (350 - p0) < TP ? (350 - p0) : TP;
      const int i0 = myp, i1 = myp + 8, i2 = myp + 16, i3 = myp + 24;
      float4 pr0, pr1, pr2, pr3;
      const float* base = preVd + (size_t)(g * kNP + p0) * 128 + c4;
      pr0 = *(const float4*)(base + (size_t)i0 * 128);
      pr1 = *(const float4*)(base + (size_t)i1 * 128);
      pr2 = *(const float4*)(base + (size_t)i2 * 128);
      if (i3 < np) pr3 = *(const float4*)(base + (size_t)i3 * 128);
      ln_relu_store(gemm20(w, &s_rfu[i0 * 20], addf4(pres4, pr0)), g4, be4, &s_a[i0 * 132 + c4]);
      ln_relu_store(gemm20(w, &s_rfu[i1 * 20], addf4(pres4, pr1)), g4, be4, &s_a[i1 * 132 + c4]);
      ln_relu_store(gemm20(w, &s_rfu[i2 * 20], addf4(pres4, pr2)), g4, be4, &s_a[i2 * 132 + c4]);
      if (i3 < np)
        ln_relu_store(gemm20(w, &s_rfu[i3 * 20], addf4(pres4, pr3)), g4, be4, &s_a[i3 * 132 + c4]);
      __syncthreads();
      // --- alpha-weighted V accumulation + rf(next) ---
      for (int p = 0; p < np; ++p) {
        float av = s_a[p * 132 + dd_];
        float4 alA = *(float4*)&s_logit[(p0 + p) * 16 + hb8];
        float4 alB = *(float4*)&s_logit[(p0 + p) * 16 + hb8 + 4];
        accv0 += alA.x * av; accv1 += alA.y * av;
        accv2 += alA.z * av; accv3 += alA.w * av;
        accv4 += alB.x * av; accv5 += alB.y * av;
        accv6 += alB.z * av; accv7 += alB.w * av;
      }
      {
        const int nxt = (tile + 1 == NT) ? 0 : tile + 1;
        const int q0p = nxt * TP;
        const int nq = (350 - q0p) < TP ? (350 - q0p) : TP;
        for (int o = t; o < nq * 20; o += 256) {
          int pp = o / 20;
          float dd2 = s_dist[q0p + pp] - (o - pp * 20) * kStep;
          s_rfu[o] = __expf(kCoeff * dd2 * dd2);
        }
      }
      __syncthreads();
    }
  }

  // =============== pass 2b: xv sweep ===============
  float ax0 = 0.f, ax1 = 0.f, ax2 = 0.f, ax3 = 0.f, ax4 = 0.f, ax5 = 0.f;
  {
    const W20 w = load_w20(xv_w1, c4);
    const float4 g4 = *(const float4*)(xv_g + c4);
    const float4 be4 = *(const float4*)(xv_be + c4);
    const float4 pres4 = *(const float4*)(preXs + (size_t)ligidx * 128 + c4);
    const int p_ = t & 31;
    const int h0 = (t >> 5) * 2, h1 = h0 + 1;

    for (int tile = 0; tile < NT; ++tile) {
      const int p0 = tile * TP;
      const int np = (350 - p0) < TP ? (350 - p0) : TP;
      const int i0 = myp, i1 = myp + 8, i2 = myp + 16, i3 = myp + 24;
      float4 pr0, pr1, pr2, pr3;
      const float* base = preXd + (size_t)(g * kNP + p0) * 128 + c4;
      pr0 = *(const float4*)(base + (size_t)i0 * 128);
      pr1 = *(const float4*)(base + (size_t)i1 * 128);
      pr2 = *(const float4*)(base + (size_t)i2 * 128);
      if (i3 < np) pr3 = *(const float4*)(base + (size_t)i3 * 128);
      ln_relu_store(gemm20(w, &s_rfu[i0 * 20], addf4(pres4, pr0)), g4, be4, &s_a[i0 * 132 + c4]);
      ln_relu_store(gemm20(w, &s_rfu[i1 * 20], addf4(pres4, pr1)), g4, be4, &s_a[i1 * 132 + c4]);
      ln_relu_store(gemm20(w, &s_rfu[i2 * 20], addf4(pres4, pr2)), g4, be4, &s_a[i2 * 132 + c4]);
      if (i3 < np)
        ln_relu_store(gemm20(w, &s_rfu[i3 * 20], addf4(pres4, pr3)), g4, be4, &s_a[i3 * 132 + c4]);
      __syncthreads();
      // --- xv projection + alpha + rel_x, half-wave shuffle reduce ---
      {
        float f0 = 0.f, f1 = 0.f;
#pragma unroll
        for (int d = 0; d < 128; d += 4) {
          float4 a4 = *(float4*)&s_a[p_ * 132 + d];
          float4 q0 = *(float4*)&s_qw[h0 * 132 + d];
          float4 q1 = *(float4*)&s_qw[h1 * 132 + d];
          f0 += a4.x * q0.x + a4.y * q0.y + a4.z * q0.z + a4.w * q0.w;
          f1 += a4.x * q1.x + a4.y * q1.y + a4.z * q1.z + a4.w * q1.w;
        }
        float w0 = 0.f, w1 = 0.f, r0 = 0.f, r1 = 0.f, r2 = 0.f;
        if (p_ < np) {
          int pg = p0 + p_;
          w0 = s_logit[pg * 16 + h0] * (f0 + s_qb[h0]);
          w1 = s_logit[pg * 16 + h1] * (f1 + s_qb[h1]);
          const float* xp = x + (size_t)(g * kNG + pg) * 3;
          r0 = lx0 - xp[0]; r1 = lx1 - xp[1]; r2 = lx2 - xp[2];
        }
        float p00 = w0 * r0, p01 = w0 * r1, p02 = w0 * r2;
        float p10 = w1 * r0, p11 = w1 * r1, p12 = w1 * r2;
#pragma unroll
        for (int m = 16; m; m >>= 1) {
          p00 += __shfl_xor(p00, m); p01 += __shfl_xor(p01, m); p02 += __shfl_xor(p02, m);
          p10 += __shfl_xor(p10, m); p11 += __shfl_xor(p11, m); p12 += __shfl_xor(p12, m);
        }
        ax0 += p00; ax1 += p01; ax2 += p02;
        ax3 += p10; ax4 += p11; ax5 += p12;
      }
      {
        const int nxt = (tile + 1 == NT) ? 0 : tile + 1;
        const int q0p = nxt * TP;
        const int nq = (350 - q0p) < TP ? (350 - q0p) : TP;
        for (int o = t; o < nq * 20; o += 256) {
          int pp = o / 20;
          float dd2 = s_dist[q0p + pp] - (o - pp * 20) * kStep;
          s_rfu[o] = __expf(kCoeff * dd2 * dd2);
        }
      }
      __syncthreads();
    }
  }

  // =============== epilogue ===============
  s_a[(hb8 + 0) * 132 + dd_] = accv0;
  s_a[(hb8 + 1) * 132 + dd_] = accv1;
  s_a[(hb8 + 2) * 132 + dd_] = accv2;
  s_a[(hb8 + 3) * 132 + dd_] = accv3;
  s_a[(hb8 + 4) * 132 + dd_] = accv4;
  s_a[(hb8 + 5) * 132 + dd_] = accv5;
  s_a[(hb8 + 6) * 132 + dd_] = accv6;
  s_a[(hb8 + 7) * 132 + dd_] = accv7;
  {
    const int h0 = (t >> 5) * 2;
    if ((t & 31) == 0) {
      s_outx[h0 * 4 + 0] = ax0; s_outx[h0 * 4 + 1] = ax1; s_outx[h0 * 4 + 2] = ax2;
      s_outx[(h0 + 1) * 4 + 0] = ax3; s_outx[(h0 + 1) * 4 + 1] = ax4;
      s_outx[(h0 + 1) * 4 + 2] = ax5;
    }
  }
  __syncthreads();

  if (t < 128) {
    float o = hv_b2[t];
    const int hh = t >> 3;
    for (int d = 0; d < 128; ++d) o += s_a[hh * 132 + d] * hv_w2[(size_t)d * 128 + t];
    s_outv[t] = o;
  }
  if (t >= 128 && t < 131) {
    int c = t - 128;
    float sm = 0.f;
#pragma unroll
    for (int hh = 0; hh < 16; ++hh) sm += s_outx[hh * 4 + c];
    xout[(size_t)lignode * 3 + c] = x[(size_t)lignode * 3 + c] + sm * (1.f / 16.f);
  }
  __syncthreads();
  float yn = 0.f;
  if (t < 128) {
    yn = no_b1[t];
    for (int i = 0; i < 128; ++i) yn += s_outv[i] * no_w1[(size_t)i * 128 + t];
    const float* h1 = h + 128;  // h row 1 (mask_ligand int gather, faithful to source)
    for (int i = 0; i < 128; ++i) yn += h1[i] * no_w1[(size_t)(128 + i) * 128 + t];
    s_tmp[t] = yn;
  }
  __syncthreads();
  if (t < 64) {
    float v0 = s_tmp[t], v1 = s_tmp[t + 64];
    float s = v0 + v1, ss = v0 * v0 + v1 * v1;
#pragma unroll
    for (int off = 32; off; off >>= 1) { s += __shfl_xor(s, off); ss += __shfl_xor(ss, off); }
    if (t == 0) {
      float mu = s / 128.f;
      s_red[0] = mu;
      s_red[1] = rsqrtf(ss / 128.f - mu * mu + 1e-5f);
    }
  }
  __syncthreads();
  if (t < 128) {
    float a = (yn - s_red[0]) * s_red[1] * no_g[t] + no_be[t];
    s_outv[t] = fmaxf(a, 0.f);
  }
  __syncthreads();
  if (t < 128) {
    float o = no_b2[t];
    for (int d = 0; d < 128; ++d) o += s_outv[d] * no_w2[(size_t)d * 128 + t];
    hout[(size_t)lignode * 128 + t] = o + h[(size_t)lignode * 128 + t];
  }
}

// ---------------------------------------------------------------------------
extern "C" void kernel_launch(void* const* d_in, const int* in_sizes, int n_in,
                              void* d_out, int out_size, void* d_ws, size_t ws_size,
                              hipStream_t stream) {
  (void)in_sizes; (void)n_in; (void)out_size; (void)ws_size;
  const float* h = (const float*)d_in[0];
  const float* x = (const float*)d_in[1];
  const float* hk_w1 = (const float*)d_in[5];
  const float* hk_b1 = (const float*)d_in[6];
  const float* hk_g  = (const float*)d_in[7];
  const float* hk_be = (const float*)d_in[8];
  const float* hk_w2 = (const float*)d_in[9];
  const float* hk_b2 = (const float*)d_in[10];
  const float* hv_w1 = (const float*)d_in[11];
  const float* hv_b1 = (const float*)d_in[12];
  const float* hv_g  = (const float*)d_in[13];
  const float* hv_be = (const float*)d_in[14];
  const float* hv_w2 = (const float*)d_in[15];
  const float* hv_b2 = (const float*)d_in[16];
  const float* xv_w1 = (const float*)d_in[17];
  const float* xv_b1 = (const float*)d_in[18];
  const float* xv_g  = (const float*)d_in[19];
  const float* xv_be = (const float*)d_in[20];
  const float* xv_w2 = (const float*)d_in[21];
  const float* xv_b2 = (const float*)d_in[22];
  const float* hq_w1 = (const float*)d_in[23];
  const float* hq_b1 = (const float*)d_in[24];
  const float* hq_g  = (const float*)d_in[25];
  const float* hq_be = (const float*)d_in[26];
  const float* hq_w2 = (const float*)d_in[27];
  const float* hq_b2 = (const float*)d_in[28];
  const float* no_w1 = (const float*)d_in[29];
  const float* no_b1 = (const float*)d_in[30];
  const float* no_g  = (const float*)d_in[31];
  const float* no_be = (const float*)d_in[32];
  const float* no_w2 = (const float*)d_in[33];
  const float* no_b2 = (const float*)d_in[34];

  float* ws = (float*)d_ws;
  float* preKd = ws;
  float* preVd = preKd + (size_t)kNPROT * 128;
  float* preXd = preVd + (size_t)kNPROT * 128;
  float* preKs = preXd + (size_t)kNPROT * 128;
  float* preVs = preKs + (size_t)kNLIG * 128;
  float* preXs = preVs + (size_t)kNLIG * 128;
  float* cvec  = preXs + (size_t)kNLIG * 128;

  float* hout = (float*)d_out;
  float* xout = hout + (size_t)kN * 128;

  pre_kernel<<<dim3(190, 3), dim3(256), 0, stream>>>(
      h, hk_w1, hk_b1, hv_w1, hv_b1, xv_w1, xv_b1,
      preKd, preVd, preXd, preKs, preVs, preXs);
  cvec_kernel<<<dim3(1), dim3(128), 0, stream>>>(
      h, no_w1, no_b1, no_g, no_be, no_w2, no_b2, cvec);
  edge_kernel<<<dim3(960), dim3(256), 0, stream>>>(
      h, x, preKd, preVd, preXd, preKs, preVs, preXs,
      hk_w1, hk_g, hk_be, hk_w2, hk_b2,
      hv_w1, hv_g, hv_be, hv_w2, hv_b2,
      xv_w1, xv_g, xv_be, xv_w2, xv_b2,
      hq_w1, hq_b1, hq_g, hq_be, hq_w2, hq_b2,
      no_w1, no_b1, no_g, no_be, no_w2, no_b2,
      hout, xout);
  prot_kernel<<<dim3(1400), dim3(256), 0, stream>>>(h, x, cvec, hout, xout);
}